// Round 13
// baseline (110.116 us; speedup 1.0000x reference)
//
#include <hip/hip_runtime.h>
#include <hip/hip_bf16.h>

typedef __attribute__((ext_vector_type(8))) short short8;
typedef __attribute__((ext_vector_type(4))) float f32x4;

#define TEMP_INV 20.0f
#define NCH 514

__device__ inline unsigned short f2bf(float f){
    unsigned int u = __builtin_bit_cast(unsigned int, f);
    u += 0x7fffu + ((u >> 16) & 1u);
    return (unsigned short)(u >> 16);
}
__device__ inline unsigned int pk2bf(float a, float b){
    return (unsigned int)f2bf(a) | ((unsigned int)f2bf(b) << 16);
}

#define GLOAD16(src, dst) __builtin_amdgcn_global_load_lds( \
    (const __attribute__((address_space(1))) unsigned int*)(src), \
    (__attribute__((address_space(3))) unsigned int*)(dst), 16, 0, 0)

// ---------------------------------------------------------------------------
// k_norm: normalize query rows -> bf16 A, pre-swizzled per-64-col K-chunk
// tiles [12][256 rows][64] (slot = g ^ (row&7)) so k_main stages linearly
// via global_load_lds. Zeroes out[0] (k_lse atomicAdds into it).
// ---------------------------------------------------------------------------
__global__ __launch_bounds__(256) void k_norm(const float* __restrict__ q,
                                              unsigned short* __restrict__ Aswz,
                                              float* __restrict__ out){
    int b = blockIdx.x, t = threadIdx.x;
    if (b == 0 && t == 0) out[0] = 0.f;
    const float* qr = q + b * 768;
    float v0 = qr[t], v1 = qr[t + 256], v2 = qr[t + 512];
    float ss = v0*v0 + v1*v1 + v2*v2;
#pragma unroll
    for (int o = 32; o; o >>= 1) ss += __shfl_xor(ss, o);
    __shared__ float red[4];
    if ((t & 63) == 0) red[t >> 6] = ss;
    __syncthreads();
    ss = red[0] + red[1] + red[2] + red[3];
    float inv = 1.0f / fmaxf(sqrtf(ss), 1e-8f);
    float nv[3] = {v0 * inv, v1 * inv, v2 * inv};
#pragma unroll
    for (int j = 0; j < 3; j++){
        int cc = t + 256 * j;
        unsigned short hh = f2bf(nv[j]);
        int kc = cc >> 6, kl = cc & 63, g = kl >> 3, e = kl & 7;
        int slot = g ^ (b & 7);
        Aswz[kc * 16384 + b * 64 + slot * 8 + e] = hh;
    }
}

// ---------------------------------------------------------------------------
// k_main: m97-geometry port. 1028 blocks x 256 threads (4 waves, 2m x 2n of
// 64x64, acc[4][4]): block = (row-tile ar of 128 queries) x (128 B-cols).
// bc<512: B-cols = queue rows [128bc,+128); bc>=512: B-cols = keys (sim_pos
// + diag), identical path with on-the-fly normalization (ssq -> invn).
// A staged 16KB/kc via global_load_lds (pre-swizzled); B: 8xfloat4 -> ssq ->
// bf16 -> 4 swizzled ds_write_b128 (even 8-lane/quad distribution = LDS
// floor). Plain 2-barrier K-loop, kc ROLLED (#pragma unroll 1 - R9: full
// unroll spilled 109 MB). ~164 unified regs -> 3 blocks/CU resident; sibling
// blocks hide stage/barrier stalls (m114/m97).
// ---------------------------------------------------------------------------
__global__ __launch_bounds__(256) void k_main(
        const float* __restrict__ keys,
        const float* __restrict__ queue,
        const unsigned short* __restrict__ Aswz,
        float* __restrict__ pmax,
        float* __restrict__ psum,
        float* __restrict__ diag){
    __shared__ unsigned short Atile[8192];   // 16 KB [128][64] swizzled
    __shared__ unsigned short Btile[8192];   // 16 KB [128][64] swizzled
    __shared__ float invn[128];
    __shared__ float redm[2][128];
    __shared__ float reds[2][128];

    const int b = blockIdx.x, t = threadIdx.x;
    const int bc = b >> 1, ar = b & 1;
    const bool keyb = (bc >= 512);
    const int colBase = (keyb ? (bc - 512) : bc) * 128;
    const int lane = t & 63;
    const int w = t >> 6;                 // 0..3
    const int wm = w >> 1, wn = w & 1;    // 2m x 2n waves, each 64x64
    const int frow = lane & 15, fg = lane >> 4;
    const int c = t >> 1, h = t & 1;      // B staging: 2 threads/col, 32 elems

    const float* src = (keyb ? keys : queue) + (size_t)(colBase + c) * 768 + h * 32;

    float ssq = 0.f;
    f32x4 acc[4][4];
#pragma unroll
    for (int i = 0; i < 4; i++)
#pragma unroll
        for (int j = 0; j < 4; j++) acc[i][j] = (f32x4)0.f;

#pragma unroll 1
    for (int kc = 0; kc < 12; ++kc){
        if (kc) __syncthreads();
        // stage A(kc): 4 x 16B per thread, linear (pre-swizzled in ws)
#pragma unroll
        for (int i = 0; i < 4; ++i)
            GLOAD16(Aswz + kc * 16384 + ar * 8192 + i * 2048 + t * 8,
                    Atile + i * 2048 + t * 8);
        // stage B(kc): 32 f32 -> ssq -> bf16 -> 4 swizzled ds_write_b128
        {
            float4 u[8];
#pragma unroll
            for (int j = 0; j < 8; ++j)
                u[j] = *(const float4*)(src + kc * 64 + j * 4);
#pragma unroll
            for (int j = 0; j < 8; ++j)
                ssq += u[j].x*u[j].x + u[j].y*u[j].y + u[j].z*u[j].z + u[j].w*u[j].w;
#pragma unroll
            for (int j = 0; j < 4; ++j){
                uint4 pk;
                pk.x = pk2bf(u[2*j].x,   u[2*j].y);
                pk.y = pk2bf(u[2*j].z,   u[2*j].w);
                pk.z = pk2bf(u[2*j+1].x, u[2*j+1].y);
                pk.w = pk2bf(u[2*j+1].z, u[2*j+1].w);
                int idx8 = h * 4 + j;
                int slot = idx8 ^ (c & 7);
                *(uint4*)&Btile[c * 64 + slot * 8] = pk;
            }
        }
        __syncthreads();   // drains gload_lds vmcnt + ds_write lgkm

        // MFMA over this K-chunk: 2 ks x 4 fm x 4 fn
#pragma unroll
        for (int ks = 0; ks < 2; ++ks){
            const int slotv = (ks * 4 + fg) ^ (frow & 7);
            short8 af[4], bfv[4];
#pragma unroll
            for (int fm = 0; fm < 4; ++fm)
                af[fm] = *(const short8*)&Atile[(wm * 64 + fm * 16 + frow) * 64 + slotv * 8];
#pragma unroll
            for (int fn = 0; fn < 4; ++fn)
                bfv[fn] = *(const short8*)&Btile[(wn * 64 + fn * 16 + frow) * 64 + slotv * 8];
#pragma unroll
            for (int fm = 0; fm < 4; ++fm)
#pragma unroll
                for (int fn = 0; fn < 4; ++fn)
                    acc[fm][fn] = __builtin_amdgcn_mfma_f32_16x16x32_bf16(
                        af[fm], bfv[fn], acc[fm][fn], 0, 0, 0);
        }
    }

    // ---- epilogue: B-col norms, scale, per-row max/sumexp partials ----
    ssq += __shfl_xor(ssq, 1);                 // pair (h=0,1) share col c
    if (h == 0) invn[c] = 1.0f / fmaxf(sqrtf(ssq), 1e-8f);
    __syncthreads();

#pragma unroll
    for (int fm = 0; fm < 4; ++fm){
#pragma unroll
        for (int rr = 0; rr < 4; ++rr){
            int row = wm * 64 + fm * 16 + fg * 4 + rr;
            float v[4];
#pragma unroll
            for (int fn = 0; fn < 4; ++fn){
                int col = wn * 64 + fn * 16 + frow;
                v[fn] = acc[fm][fn][rr] * invn[col] * TEMP_INV;
                if (keyb && (ar * 128 + row) == (colBase + col))
                    diag[ar * 128 + row] = v[fn];
            }
            float m = fmaxf(fmaxf(v[0], v[1]), fmaxf(v[2], v[3]));
#pragma unroll
            for (int o = 1; o < 16; o <<= 1) m = fmaxf(m, __shfl_xor(m, o));
            float s = __expf(v[0]-m) + __expf(v[1]-m) + __expf(v[2]-m) + __expf(v[3]-m);
#pragma unroll
            for (int o = 1; o < 16; o <<= 1) s += __shfl_xor(s, o);
            if (frow == 0){ redm[wn][row] = m; reds[wn][row] = s; }
        }
    }
    __syncthreads();
    if (t < 128){
        float m0 = redm[0][t], m1 = redm[1][t];
        float M = fmaxf(m0, m1);
        float S = reds[0][t] * __expf(m0 - M) + reds[1][t] * __expf(m1 - M);
        pmax[bc * 256 + ar * 128 + t] = M;
        psum[bc * 256 + ar * 128 + t] = S;
    }
}

// ---------------------------------------------------------------------------
// k_lse: per q-row, merge 514 chunk partials; atomicAdd loss contribution.
// ---------------------------------------------------------------------------
__global__ __launch_bounds__(256) void k_lse(const float* __restrict__ pmax,
                                             const float* __restrict__ psum,
                                             const float* __restrict__ diag,
                                             float* __restrict__ out){
    int b = blockIdx.x, t = threadIdx.x;
    float m = -1e30f;
    for (int cc = t; cc < NCH; cc += 256) m = fmaxf(m, pmax[cc * 256 + b]);
#pragma unroll
    for (int o = 32; o; o >>= 1) m = fmaxf(m, __shfl_xor(m, o));
    __shared__ float red[4];
    __shared__ float Msh;
    if ((t & 63) == 0) red[t >> 6] = m;
    __syncthreads();
    if (t == 0) Msh = fmaxf(fmaxf(red[0], red[1]), fmaxf(red[2], red[3]));
    __syncthreads();
    float M = Msh;
    float s = 0.f;
    for (int cc = t; cc < NCH; cc += 256) s += psum[cc * 256 + b] * __expf(pmax[cc * 256 + b] - M);
#pragma unroll
    for (int o = 32; o; o >>= 1) s += __shfl_xor(s, o);
    if ((t & 63) == 0) red[t >> 6] = s;
    __syncthreads();
    if (t == 0)
        atomicAdd(out, (M + logf(red[0] + red[1] + red[2] + red[3]) - diag[b]) * (1.0f / 256.0f));
}

extern "C" void kernel_launch(void* const* d_in, const int* in_sizes, int n_in,
                              void* d_out, int out_size, void* d_ws, size_t ws_size,
                              hipStream_t stream){
    const float* q  = (const float*)d_in[0];
    const float* k  = (const float*)d_in[1];
    const float* qu = (const float*)d_in[2];
    char* ws = (char*)d_ws;
    // ws layout (bytes): Aswz 0..393216 | diag ..394240 |
    //                    pmax ..920576 | psum ..1446912
    unsigned short* Aswz = (unsigned short*)(ws);
    float* diag  = (float*)(ws + 393216);
    float* pmax  = (float*)(ws + 394240);
    float* psum  = (float*)(ws + 920576);

    k_norm<<<256, 256, 0, stream>>>(q, Aswz, (float*)d_out);
    k_main<<<1028, 256, 0, stream>>>(k, qu, Aswz, pmax, psum, diag);
    k_lse<<<256, 256, 0, stream>>>(pmax, psum, diag, (float*)d_out);
}